// Round 4
// baseline (329.512 us; speedup 1.0000x reference)
//
#include <hip/hip_runtime.h>
#include <math.h>

#define NQ 4
#define NL 2

typedef __attribute__((ext_vector_type(8))) short short8v;  // 8 x bf16 (4 VGPRs)
typedef __attribute__((ext_vector_type(4))) float f32x4;

__device__ inline unsigned short f2bf(float x){
    unsigned u = __float_as_uint(x);
    u += 0x7FFFu + ((u >> 16) & 1u);          // RNE
    return (unsigned short)(u >> 16);
}
__device__ inline float bf2f(unsigned short h){
    return __uint_as_float(((unsigned)h) << 16);
}
// split x into hi (bf16) + lo (bf16 of residual); 3-term MFMA keeps ~fp32 accuracy
__device__ inline void split8(const float* x, short8v& hi, short8v& lo){
    #pragma unroll
    for (int e = 0; e < 8; ++e){
        unsigned short h = f2bf(x[e]);
        hi[e] = (short)h;
        lo[e] = (short)f2bf(x[e] - bf2f(h));
    }
}

// ---------------------------------------------------------------------------
// Kernel 1: precompute A = Re(M^dagger D M)  (unchanged, verified)
// ---------------------------------------------------------------------------
__global__ void qnn_precompute_A(const float* __restrict__ qw, float* __restrict__ A)
{
    __shared__ float Mre[16][16];
    __shared__ float Mim[16][16];
    int t = threadIdx.x;
    if (t < 16) {
        int j = t;
        float re[16], im[16];
        for (int b = 0; b < 16; ++b) { re[b] = (b == j) ? 1.f : 0.f; im[b] = 0.f; }
        for (int l = 0; l < NL; ++l) {
            for (int i = 0; i < NQ; ++i) {
                float phi   = qw[(l*NQ + i)*3 + 0];
                float theta = qw[(l*NQ + i)*3 + 1];
                float omega = qw[(l*NQ + i)*3 + 2];
                float ct, st; sincosf(0.5f*theta, &st, &ct);
                float ap = 0.5f*(phi + omega);
                float am = 0.5f*(phi - omega);
                float cap, sap, cam, sam;
                sincosf(ap, &sap, &cap);
                sincosf(am, &sam, &cam);
                float u00r =  cap*ct, u00i = -sap*ct;
                float u01r = -cam*st, u01i = -sam*st;
                float u10r =  cam*st, u10i = -sam*st;
                float u11r =  cap*ct, u11i =  sap*ct;
                int mask = 1 << (3 - i);
                for (int b = 0; b < 16; ++b) {
                    if (b & mask) continue;
                    int b1 = b | mask;
                    float a0r = re[b],  a0i = im[b];
                    float a1r = re[b1], a1i = im[b1];
                    re[b]  = u00r*a0r - u00i*a0i + u01r*a1r - u01i*a1i;
                    im[b]  = u00r*a0i + u00i*a0r + u01r*a1i + u01i*a1r;
                    re[b1] = u10r*a0r - u10i*a0i + u11r*a1r - u11i*a1i;
                    im[b1] = u10r*a0i + u10i*a0r + u11r*a1i + u11i*a1r;
                }
            }
            for (int b = 0; b < 16; ++b) {
                float sgn = 1.f;
                if ((b & 0xC) == 0xC) sgn = -sgn;
                if ((b & 0x6) == 0x6) sgn = -sgn;
                if ((b & 0x3) == 0x3) sgn = -sgn;
                re[b] *= sgn; im[b] *= sgn;
            }
        }
        for (int b = 0; b < 16; ++b) { Mre[j][b] = re[b]; Mim[j][b] = im[b]; }
    }
    __syncthreads();
    {
        int j = t >> 4, k = t & 15;
        float s = 0.f;
        #pragma unroll
        for (int b = 0; b < 16; ++b) {
            float sg = (b & 8) ? -1.f : 1.f;
            s += sg * (Mre[j][b]*Mre[k][b] + Mim[j][b]*Mim[k][b]);
        }
        A[j*16 + k] = s;
    }
}

// ---------------------------------------------------------------------------
// helpers for kernel 2
// ---------------------------------------------------------------------------
__device__ inline void po_update(float (&po)[4][4], const f32x4& cc, const float4& w2){
    #pragma unroll
    for (int r = 0; r < 4; ++r){
        float h = fmaxf(cc[r], 0.f);
        po[r][0] = fmaf(h, w2.x, po[r][0]);
        po[r][1] = fmaf(h, w2.y, po[r][1]);
        po[r][2] = fmaf(h, w2.z, po[r][2]);
        po[r][3] = fmaf(h, w2.w, po[r][3]);
    }
}
__device__ inline void reduce_po(float (&po)[4][4]){
    #pragma unroll
    for (int r = 0; r < 4; ++r)
        #pragma unroll
        for (int o = 0; o < 4; ++o){
            float v = po[r][o];
            v += __shfl_xor(v, 1);
            v += __shfl_xor(v, 2);
            v += __shfl_xor(v, 4);
            v += __shfl_xor(v, 8);
            po[r][o] = v;
        }
}
__device__ inline float4 pick_row(const float (&po)[4][4], int c){
    float4 v;
    if      (c == 0) v = make_float4(po[0][0], po[0][1], po[0][2], po[0][3]);
    else if (c == 1) v = make_float4(po[1][0], po[1][1], po[1][2], po[1][3]);
    else if (c == 2) v = make_float4(po[2][0], po[2][1], po[2][2], po[2][3]);
    else             v = make_float4(po[3][0], po[3][1], po[3][2], po[3][3]);
    return v;
}
// image A-frags: K=48 zero-padded to 64 (2 k-steps); k-slot map k = ks*32+8*g+e
__device__ inline void build_imgA(const float* irow, int g,
                                  short8v& Aih0, short8v& Ail0,
                                  short8v& Aih1, short8v& Ail1){
    float x[8];
    float4 v0 = *(const float4*)(irow + 8*g);
    float4 v1 = *(const float4*)(irow + 8*g + 4);
    x[0]=v0.x; x[1]=v0.y; x[2]=v0.z; x[3]=v0.w;
    x[4]=v1.x; x[5]=v1.y; x[6]=v1.z; x[7]=v1.w;
    split8(x, Aih0, Ail0);
    float xi[8];
    #pragma unroll
    for (int e = 0; e < 8; ++e) xi[e] = 0.f;
    if (g < 2){
        float4 v2 = *(const float4*)(irow + 32 + 8*g);
        float4 v3 = *(const float4*)(irow + 32 + 8*g + 4);
        xi[0]=v2.x; xi[1]=v2.y; xi[2]=v2.z; xi[3]=v2.w;
        xi[4]=v3.x; xi[5]=v3.y; xi[6]=v3.z; xi[7]=v3.w;
    }
    split8(xi, Aih1, Ail1);
}
// text A-frags: K=16 zero-padded to 32
__device__ inline void build_txtA(const float* trow, int g, short8v& Ath, short8v& Atl){
    float xt[8];
    #pragma unroll
    for (int e = 0; e < 8; ++e) xt[e] = 0.f;
    if (g < 2){
        float4 t0 = *(const float4*)(trow + 8*g);
        float4 t1 = *(const float4*)(trow + 8*g + 4);
        xt[0]=t0.x; xt[1]=t0.y; xt[2]=t0.z; xt[3]=t0.w;
        xt[4]=t1.x; xt[5]=t1.y; xt[6]=t1.z; xt[7]=t1.w;
    }
    split8(xt, Ath, Atl);
}

// ---------------------------------------------------------------------------
// Kernel 2: MFMA with weight fragments in LDS.
// Rounds 2/3 failed on register pressure: wave-resident bf16 weight
// fragments (even chunked) pushed past the VGPR budget -> ~180 B/thread
// scratch spill (WRITE_SIZE 98 MB vs 4 MB real output), occupancy 43%.
// Fix: weights are block-shared, so stage ALL weight fragments (pre-split
// hi/lo bf16, MFMA k-slot layout) into LDS once per block, cooperatively.
// Each MFMA then reads its 16B B-operand with one ds_read_b128
// (lane*16B addresses -> 2-way bank aliasing = free). This removes ~64
// VGPRs of resident weights AND the per-wave weight split8, and restores a
// single pass over the image input (no chunk re-read).
// LDS: 20 KB weight frags + 4 KB feats = 24 KB -> 6 blocks/CU cap.
// Per-thread live set: A-frags 24 + po 16 + temps ~30 -> fits (256,4)
// budget with no scratch.
// Phase 2 per-thread quantum quadratic form + head unchanged (verified).
// ---------------------------------------------------------------------------
__global__ __launch_bounds__(256, 4) void qnn_main(
    const float* __restrict__ text, const float* __restrict__ image,
    const float* __restrict__ tW1, const float* __restrict__ tb1,
    const float* __restrict__ tW2, const float* __restrict__ tb2,
    const float* __restrict__ iW1, const float* __restrict__ ib1,
    const float* __restrict__ iW2, const float* __restrict__ ib2,
    const float* __restrict__ A,
    const float* __restrict__ cW1, const float* __restrict__ cb1,
    const float* __restrict__ cW2, const float* __restrict__ cb2,
    float* __restrict__ out, int B)
{
    __shared__ short8v WimgH[4][2][64];   // [nt][ks][lane]  8 KB
    __shared__ short8v WimgL[4][2][64];   //                 8 KB
    __shared__ short8v WtxtH[2][64];      // [nt][lane]      2 KB
    __shared__ short8v WtxtL[2][64];      //                 2 KB
    __shared__ float4  feats[256];        //                 4 KB

    const int t    = threadIdx.x;
    const int lane = t & 63;
    const int wv   = t >> 6;
    const int g    = lane >> 4;   // k-slot group
    const int c    = lane & 15;   // A row (sample) / B col (neuron) / D col
    const long long blockBase = (long long)blockIdx.x * 256;

    // ---------- cooperative weight-fragment staging (once per block) --------
    // image: 512 frag slots (nt,ks,lane); each thread fills 2
    #pragma unroll
    for (int s = t; s < 512; s += 256){
        int nt = s >> 7, ks = (s >> 6) & 1, ln = s & 63;
        int gg = ln >> 4, cc_ = ln & 15;
        float x[8];
        #pragma unroll
        for (int e = 0; e < 8; ++e){
            int k = ks*32 + 8*gg + e;
            x[e] = (k < 48) ? iW1[k*64 + nt*16 + cc_] : 0.f;
        }
        short8v h, l; split8(x, h, l);
        WimgH[nt][ks][ln] = h;
        WimgL[nt][ks][ln] = l;
    }
    // text: 128 frag slots (nt,lane); threads 0..127 fill one each
    if (t < 128){
        int nt = t >> 6, ln = t & 63;
        int gg = ln >> 4, cc_ = ln & 15;
        float x[8];
        #pragma unroll
        for (int e = 0; e < 8; ++e){
            int k = 8*gg + e;
            x[e] = (k < 16) ? tW1[k*32 + nt*16 + cc_] : 0.f;
        }
        short8v h, l; split8(x, h, l);
        WtxtH[nt][ln] = h;
        WtxtL[nt][ln] = l;
    }
    __syncthreads();

    // per-lane layer-1 biases (hoisted)
    float bImg[4], bTxt[2];
    #pragma unroll
    for (int nt = 0; nt < 4; ++nt) bImg[nt] = ib1[nt*16 + c];
    #pragma unroll
    for (int nt = 0; nt < 2; ++nt) bTxt[nt] = tb1[nt*16 + c];

    // ---------------- main loop: 4 M-tiles of 16 samples per wave -----------
    #pragma unroll 1
    for (int ms = 0; ms < 4; ++ms){
        long long m = blockBase + wv*64 + ms*16 + c;
        if (m >= B) m = B - 1;                    // clamp (phase-2 guards output)
        short8v Aih[2], Ail[2], Ath, Atl;
        build_imgA(image + m*48, g, Aih[0], Ail[0], Aih[1], Ail[1]);
        build_txtA(text  + m*16, g, Ath, Atl);

        float po[4][4];
        #pragma unroll
        for (int r = 0; r < 4; ++r)
            #pragma unroll
            for (int o = 0; o < 4; ++o) po[r][o] = 0.f;

        // image: h2 = relu(x@iW1 + ib1); po += h2 @ iW2
        #pragma unroll
        for (int nt = 0; nt < 4; ++nt){
            float bb = bImg[nt];
            f32x4 cc = { bb, bb, bb, bb };
            #pragma unroll
            for (int ks = 0; ks < 2; ++ks){
                short8v bh = WimgH[nt][ks][lane];
                short8v bl = WimgL[nt][ks][lane];
                cc = __builtin_amdgcn_mfma_f32_16x16x32_bf16(Aih[ks], bh, cc, 0, 0, 0);
                cc = __builtin_amdgcn_mfma_f32_16x16x32_bf16(Aih[ks], bl, cc, 0, 0, 0);
                cc = __builtin_amdgcn_mfma_f32_16x16x32_bf16(Ail[ks], bh, cc, 0, 0, 0);
            }
            const float4 w2 = *(const float4*)(iW2 + (nt*16 + c)*4);
            po_update(po, cc, w2);
        }
        // text: h1 = relu(x@tW1 + tb1); po += h1 @ tW2
        #pragma unroll
        for (int nt = 0; nt < 2; ++nt){
            float bb = bTxt[nt];
            f32x4 cc = { bb, bb, bb, bb };
            short8v bh = WtxtH[nt][lane];
            short8v bl = WtxtL[nt][lane];
            cc = __builtin_amdgcn_mfma_f32_16x16x32_bf16(Ath, bh, cc, 0, 0, 0);
            cc = __builtin_amdgcn_mfma_f32_16x16x32_bf16(Ath, bl, cc, 0, 0, 0);
            cc = __builtin_amdgcn_mfma_f32_16x16x32_bf16(Atl, bh, cc, 0, 0, 0);
            const float4 w2 = *(const float4*)(tW2 + (nt*16 + c)*4);
            po_update(po, cc, w2);
        }

        reduce_po(po);
        if (c < 4)
            feats[wv*64 + ms*16 + 4*g + c] = pick_row(po, c);
    }

    __syncthreads();

    // ---------------- Phase 2: per-thread quantum form + head ---------------
    long long samp = blockBase + t;
    if (samp < B){
        float4 f4 = feats[t];
        float acc[4];
        acc[0] = tb2[0] + ib2[0] + f4.x;
        acc[1] = tb2[1] + ib2[1] + f4.y;
        acc[2] = tb2[2] + ib2[2] + f4.z;
        acc[3] = tb2[3] + ib2[3] + f4.w;

        float cth[4], sth[4];
        #pragma unroll
        for (int i = 0; i < 4; ++i){
            float f = acc[i] * 0.25f;
            __sincosf(f, &sth[i], &cth[i]);
        }
        float p01[4] = { cth[0]*cth[1], cth[0]*sth[1], sth[0]*cth[1], sth[0]*sth[1] };
        float p23[4] = { cth[2]*cth[3], cth[2]*sth[3], sth[2]*cth[3], sth[2]*sth[3] };
        float psi[16];
        #pragma unroll
        for (int x = 0; x < 4; ++x)
            #pragma unroll
            for (int y = 0; y < 4; ++y)
                psi[x*4+y] = p01[x] * p23[y];

        float q = 0.f;
        #pragma unroll
        for (int j = 0; j < 16; ++j){
            float row = 0.f;
            #pragma unroll
            for (int k = 0; k < 16; ++k) row = fmaf(A[j*16+k], psi[k], row);
            q = fmaf(psi[j], row, q);
        }

        float o0 = cb2[0], o1 = cb2[1];
        #pragma unroll
        for (int j = 0; j < 16; ++j){
            float h = fmaxf(fmaf(q, cW1[j], cb1[j]), 0.f);
            o0 = fmaf(h, cW2[j*2+0], o0);
            o1 = fmaf(h, cW2[j*2+1], o1);
        }
        float2* o2 = (float2*)out;
        o2[samp] = make_float2(o0, o1);
    }
}

extern "C" void kernel_launch(void* const* d_in, const int* in_sizes, int n_in,
                              void* d_out, int out_size, void* d_ws, size_t ws_size,
                              hipStream_t stream)
{
    const float* text  = (const float*)d_in[0];
    const float* image = (const float*)d_in[1];
    const float* tW1   = (const float*)d_in[2];
    const float* tb1   = (const float*)d_in[3];
    const float* tW2   = (const float*)d_in[4];
    const float* tb2   = (const float*)d_in[5];
    const float* iW1   = (const float*)d_in[6];
    const float* ib1   = (const float*)d_in[7];
    const float* iW2   = (const float*)d_in[8];
    const float* ib2   = (const float*)d_in[9];
    const float* qw    = (const float*)d_in[10];
    const float* cW1   = (const float*)d_in[11];
    const float* cb1   = (const float*)d_in[12];
    const float* cW2   = (const float*)d_in[13];
    const float* cb2   = (const float*)d_in[14];

    float* A = (float*)d_ws;          // 256 floats
    int B = in_sizes[0] / 16;

    qnn_precompute_A<<<1, 256, 0, stream>>>(qw, A);

    int block = 256;
    int grid = (B + block - 1) / block;
    qnn_main<<<grid, block, 0, stream>>>(
        text, image, tW1, tb1, tW2, tb2, iW1, ib1, iW2, ib2,
        A, cW1, cb1, cW2, cb2, (float*)d_out, B);
}

// Round 5
// 246.070 us; speedup vs baseline: 1.3391x; 1.3391x over previous
//
#include <hip/hip_runtime.h>
#include <math.h>

#define NQ 4
#define NL 2

typedef __attribute__((ext_vector_type(8))) short short8v;  // 8 x bf16 (4 VGPRs)
typedef __attribute__((ext_vector_type(4))) float f32x4;

__device__ inline unsigned short f2bf(float x){
    unsigned u = __float_as_uint(x);
    u += 0x7FFFu + ((u >> 16) & 1u);          // RNE
    return (unsigned short)(u >> 16);
}
__device__ inline float bf2f(unsigned short h){
    return __uint_as_float(((unsigned)h) << 16);
}
// staging-path split (strided gather -> small array, static indices)
__device__ inline void split8(const float* x, short8v& hi, short8v& lo){
    #pragma unroll
    for (int e = 0; e < 8; ++e){
        unsigned short h = f2bf(x[e]);
        hi[e] = (short)h;
        lo[e] = (short)f2bf(x[e] - bf2f(h));
    }
}
// hot-path split: two float4 -> hi/lo bf16x8, fully scalar SSA
#define PK(i, val) { unsigned short h_ = f2bf(val); hi[i] = (short)h_; lo[i] = (short)f2bf((val) - bf2f(h_)); }
__device__ inline void pack8(float4 a, float4 b, short8v& hi, short8v& lo){
    PK(0, a.x) PK(1, a.y) PK(2, a.z) PK(3, a.w)
    PK(4, b.x) PK(5, b.y) PK(6, b.z) PK(7, b.w)
}
#undef PK

// ---------------------------------------------------------------------------
// Kernel 1: precompute A = Re(M^dagger D M)  (unchanged, verified)
// ---------------------------------------------------------------------------
__global__ void qnn_precompute_A(const float* __restrict__ qw, float* __restrict__ A)
{
    __shared__ float Mre[16][16];
    __shared__ float Mim[16][16];
    int t = threadIdx.x;
    if (t < 16) {
        int j = t;
        float re[16], im[16];
        for (int b = 0; b < 16; ++b) { re[b] = (b == j) ? 1.f : 0.f; im[b] = 0.f; }
        for (int l = 0; l < NL; ++l) {
            for (int i = 0; i < NQ; ++i) {
                float phi   = qw[(l*NQ + i)*3 + 0];
                float theta = qw[(l*NQ + i)*3 + 1];
                float omega = qw[(l*NQ + i)*3 + 2];
                float ct, st; sincosf(0.5f*theta, &st, &ct);
                float ap = 0.5f*(phi + omega);
                float am = 0.5f*(phi - omega);
                float cap, sap, cam, sam;
                sincosf(ap, &sap, &cap);
                sincosf(am, &sam, &cam);
                float u00r =  cap*ct, u00i = -sap*ct;
                float u01r = -cam*st, u01i = -sam*st;
                float u10r =  cam*st, u10i = -sam*st;
                float u11r =  cap*ct, u11i =  sap*ct;
                int mask = 1 << (3 - i);
                for (int b = 0; b < 16; ++b) {
                    if (b & mask) continue;
                    int b1 = b | mask;
                    float a0r = re[b],  a0i = im[b];
                    float a1r = re[b1], a1i = im[b1];
                    re[b]  = u00r*a0r - u00i*a0i + u01r*a1r - u01i*a1i;
                    im[b]  = u00r*a0i + u00i*a0r + u01r*a1i + u01i*a1r;
                    re[b1] = u10r*a0r - u10i*a0i + u11r*a1r - u11i*a1i;
                    im[b1] = u10r*a0i + u10i*a0r + u11r*a1i + u11i*a1r;
                }
            }
            for (int b = 0; b < 16; ++b) {
                float sgn = 1.f;
                if ((b & 0xC) == 0xC) sgn = -sgn;
                if ((b & 0x6) == 0x6) sgn = -sgn;
                if ((b & 0x3) == 0x3) sgn = -sgn;
                re[b] *= sgn; im[b] *= sgn;
            }
        }
        for (int b = 0; b < 16; ++b) { Mre[j][b] = re[b]; Mim[j][b] = im[b]; }
    }
    __syncthreads();
    {
        int j = t >> 4, k = t & 15;
        float s = 0.f;
        #pragma unroll
        for (int b = 0; b < 16; ++b) {
            float sg = (b & 8) ? -1.f : 1.f;
            s += sg * (Mre[j][b]*Mre[k][b] + Mim[j][b]*Mim[k][b]);
        }
        A[j*16 + k] = s;
    }
}

// ---------------------------------------------------------------------------
// helpers for kernel 2
// ---------------------------------------------------------------------------
__device__ inline void po_update(float (&po)[4][4], const f32x4& cc, const float4& w2){
    #pragma unroll
    for (int r = 0; r < 4; ++r){
        float h = fmaxf(cc[r], 0.f);
        po[r][0] = fmaf(h, w2.x, po[r][0]);
        po[r][1] = fmaf(h, w2.y, po[r][1]);
        po[r][2] = fmaf(h, w2.z, po[r][2]);
        po[r][3] = fmaf(h, w2.w, po[r][3]);
    }
}
__device__ inline void reduce_po(float (&po)[4][4]){
    #pragma unroll
    for (int r = 0; r < 4; ++r)
        #pragma unroll
        for (int o = 0; o < 4; ++o){
            float v = po[r][o];
            v += __shfl_xor(v, 1);
            v += __shfl_xor(v, 2);
            v += __shfl_xor(v, 4);
            v += __shfl_xor(v, 8);
            po[r][o] = v;
        }
}
__device__ inline float4 pick_row(const float (&po)[4][4], int c){
    float4 v;
    if      (c == 0) v = make_float4(po[0][0], po[0][1], po[0][2], po[0][3]);
    else if (c == 1) v = make_float4(po[1][0], po[1][1], po[1][2], po[1][3]);
    else if (c == 2) v = make_float4(po[2][0], po[2][1], po[2][2], po[2][3]);
    else             v = make_float4(po[3][0], po[3][1], po[3][2], po[3][3]);
    return v;
}

// one 3-term (hi*hi + hi*lo + lo*hi) MFMA step
#define STEP3(ACC, BH, BL, AH, AL)                                          \
    ACC = __builtin_amdgcn_mfma_f32_16x16x32_bf16(AH, BH, ACC, 0, 0, 0);    \
    ACC = __builtin_amdgcn_mfma_f32_16x16x32_bf16(AH, BL, ACC, 0, 0, 0);    \
    ACC = __builtin_amdgcn_mfma_f32_16x16x32_bf16(AL, BH, ACC, 0, 0, 0);

// ---------------------------------------------------------------------------
// Kernel 2: MFMA, LDS weights, SPILL-PROOFED.
// Rounds 2-4 all spilled (~150-300B/thread scratch; WRITE_SIZE 80-157MB vs
// 4MB real output) with reported arch-VGPR pinned at 64-84: the unified
// VGPR/AGPR split leaves the non-MFMA code ~64 arch regs, and the scheduler
// hoisting all 18 ds_read_b128 B-operands (72 regs) above the MFMA cluster
// blew that budget. Fixes in this version:
//  1. only ONE A-frag pair (8 regs) live at a time; persistent f32x4
//     accumulators a0..a5 carry across the 3 k-phases (AGPR-side).
//  2. sched_barrier(0) after each MFMA phase caps LDS-read hoisting to
//     <=8 B-operand regs in flight.
//  3. all 6 global input float4 loads issued at the top of each M-tile so
//     load latency is still hidden despite the barriers.
// Accumulation order per acc is identical to the verified R2-R4 math.
// ---------------------------------------------------------------------------
__global__ __launch_bounds__(256, 4) void qnn_main(
    const float* __restrict__ text, const float* __restrict__ image,
    const float* __restrict__ tW1, const float* __restrict__ tb1,
    const float* __restrict__ tW2, const float* __restrict__ tb2,
    const float* __restrict__ iW1, const float* __restrict__ ib1,
    const float* __restrict__ iW2, const float* __restrict__ ib2,
    const float* __restrict__ A,
    const float* __restrict__ cW1, const float* __restrict__ cb1,
    const float* __restrict__ cW2, const float* __restrict__ cb2,
    float* __restrict__ out, int B)
{
    __shared__ short8v WimgH[4][2][64];   // [nt][ks][lane]  8 KB
    __shared__ short8v WimgL[4][2][64];   //                 8 KB
    __shared__ short8v WtxtH[2][64];      // [nt][lane]      2 KB
    __shared__ short8v WtxtL[2][64];      //                 2 KB
    __shared__ float4  feats[256];        //                 4 KB

    const int t    = threadIdx.x;
    const int lane = t & 63;
    const int wv   = t >> 6;
    const int g    = lane >> 4;   // k-slot group
    const int c    = lane & 15;   // A row (sample) / B col (neuron) / D col
    const long long blockBase = (long long)blockIdx.x * 256;

    // ---------- cooperative weight-fragment staging (once per block) --------
    #pragma unroll
    for (int s = t; s < 512; s += 256){
        int nt = s >> 7, ks = (s >> 6) & 1, ln = s & 63;
        int gg = ln >> 4, cc_ = ln & 15;
        float x[8];
        #pragma unroll
        for (int e = 0; e < 8; ++e){
            int k = ks*32 + 8*gg + e;
            x[e] = (k < 48) ? iW1[k*64 + nt*16 + cc_] : 0.f;
        }
        short8v h, l; split8(x, h, l);
        WimgH[nt][ks][ln] = h;
        WimgL[nt][ks][ln] = l;
    }
    if (t < 128){
        int nt = t >> 6, ln = t & 63;
        int gg = ln >> 4, cc_ = ln & 15;
        float x[8];
        #pragma unroll
        for (int e = 0; e < 8; ++e){
            int k = 8*gg + e;
            x[e] = (k < 16) ? tW1[k*32 + nt*16 + cc_] : 0.f;
        }
        short8v h, l; split8(x, h, l);
        WtxtH[nt][ln] = h;
        WtxtL[nt][ln] = l;
    }
    __syncthreads();

    // per-lane layer-1 biases (6 persistent VGPRs)
    const float bI0 = ib1[c],      bI1 = ib1[16 + c];
    const float bI2 = ib1[32 + c], bI3 = ib1[48 + c];
    const float bT0 = tb1[c],      bT1 = tb1[16 + c];

    // ---------------- main loop: 4 M-tiles of 16 samples per wave -----------
    #pragma unroll 1
    for (int ms = 0; ms < 4; ++ms){
        long long m = blockBase + wv*64 + ms*16 + c;
        if (m >= B) m = B - 1;                    // clamp (phase-2 guards output)
        const float* irow = image + m*48;
        const float* trow = text  + m*16;

        // all global input loads issued up front (latency hidden under MFMA)
        const float4 z = make_float4(0.f, 0.f, 0.f, 0.f);
        float4 i0a = *(const float4*)(irow + 8*g);
        float4 i0b = *(const float4*)(irow + 8*g + 4);
        float4 i1a = z, i1b = z, t0a = z, t0b = z;
        if (g < 2){
            i1a = *(const float4*)(irow + 32 + 8*g);
            i1b = *(const float4*)(irow + 36 + 8*g);
            t0a = *(const float4*)(trow + 8*g);
            t0b = *(const float4*)(trow + 8*g + 4);
        }

        f32x4 a0 = { bI0, bI0, bI0, bI0 };
        f32x4 a1 = { bI1, bI1, bI1, bI1 };
        f32x4 a2 = { bI2, bI2, bI2, bI2 };
        f32x4 a3 = { bI3, bI3, bI3, bI3 };
        f32x4 a4 = { bT0, bT0, bT0, bT0 };
        f32x4 a5 = { bT1, bT1, bT1, bT1 };

        short8v Ah, Al;

        // ---- phase 1: image k 0..31 ----
        pack8(i0a, i0b, Ah, Al);
        { short8v bh = WimgH[0][0][lane], bl = WimgL[0][0][lane]; STEP3(a0, bh, bl, Ah, Al) }
        { short8v bh = WimgH[1][0][lane], bl = WimgL[1][0][lane]; STEP3(a1, bh, bl, Ah, Al) }
        { short8v bh = WimgH[2][0][lane], bl = WimgL[2][0][lane]; STEP3(a2, bh, bl, Ah, Al) }
        { short8v bh = WimgH[3][0][lane], bl = WimgL[3][0][lane]; STEP3(a3, bh, bl, Ah, Al) }
        __builtin_amdgcn_sched_barrier(0);

        // ---- phase 2: image k 32..47 (zero-padded to 64) ----
        pack8(i1a, i1b, Ah, Al);
        { short8v bh = WimgH[0][1][lane], bl = WimgL[0][1][lane]; STEP3(a0, bh, bl, Ah, Al) }
        { short8v bh = WimgH[1][1][lane], bl = WimgL[1][1][lane]; STEP3(a1, bh, bl, Ah, Al) }
        { short8v bh = WimgH[2][1][lane], bl = WimgL[2][1][lane]; STEP3(a2, bh, bl, Ah, Al) }
        { short8v bh = WimgH[3][1][lane], bl = WimgL[3][1][lane]; STEP3(a3, bh, bl, Ah, Al) }
        __builtin_amdgcn_sched_barrier(0);

        // ---- phase 3: text k 0..15 (zero-padded to 32) ----
        pack8(t0a, t0b, Ah, Al);
        { short8v bh = WtxtH[0][lane], bl = WtxtL[0][lane]; STEP3(a4, bh, bl, Ah, Al) }
        { short8v bh = WtxtH[1][lane], bl = WtxtL[1][lane]; STEP3(a5, bh, bl, Ah, Al) }
        __builtin_amdgcn_sched_barrier(0);

        // ---- epilogue: relu + layer-2, reduce over 16 neuron lanes ----
        float po[4][4];
        #pragma unroll
        for (int r = 0; r < 4; ++r)
            #pragma unroll
            for (int o = 0; o < 4; ++o) po[r][o] = 0.f;

        { float4 w2 = *(const float4*)(iW2 + (c)*4);      po_update(po, a0, w2); }
        { float4 w2 = *(const float4*)(iW2 + (16+c)*4);   po_update(po, a1, w2); }
        { float4 w2 = *(const float4*)(iW2 + (32+c)*4);   po_update(po, a2, w2); }
        { float4 w2 = *(const float4*)(iW2 + (48+c)*4);   po_update(po, a3, w2); }
        { float4 w2 = *(const float4*)(tW2 + (c)*4);      po_update(po, a4, w2); }
        { float4 w2 = *(const float4*)(tW2 + (16+c)*4);   po_update(po, a5, w2); }

        reduce_po(po);
        if (c < 4)
            feats[wv*64 + ms*16 + 4*g + c] = pick_row(po, c);
        __builtin_amdgcn_sched_barrier(0);
    }

    __syncthreads();

    // ---------------- Phase 2: per-thread quantum form + head ---------------
    long long samp = blockBase + t;
    if (samp < B){
        float4 f4 = feats[t];
        float acc[4];
        acc[0] = tb2[0] + ib2[0] + f4.x;
        acc[1] = tb2[1] + ib2[1] + f4.y;
        acc[2] = tb2[2] + ib2[2] + f4.z;
        acc[3] = tb2[3] + ib2[3] + f4.w;

        float cth[4], sth[4];
        #pragma unroll
        for (int i = 0; i < 4; ++i){
            float f = acc[i] * 0.25f;
            __sincosf(f, &sth[i], &cth[i]);
        }
        float p01[4] = { cth[0]*cth[1], cth[0]*sth[1], sth[0]*cth[1], sth[0]*sth[1] };
        float p23[4] = { cth[2]*cth[3], cth[2]*sth[3], sth[2]*cth[3], sth[2]*sth[3] };
        float psi[16];
        #pragma unroll
        for (int x = 0; x < 4; ++x)
            #pragma unroll
            for (int y = 0; y < 4; ++y)
                psi[x*4+y] = p01[x] * p23[y];

        float q = 0.f;
        #pragma unroll
        for (int j = 0; j < 16; ++j){
            float row = 0.f;
            #pragma unroll
            for (int k = 0; k < 16; ++k) row = fmaf(A[j*16+k], psi[k], row);
            q = fmaf(psi[j], row, q);
        }

        float o0 = cb2[0], o1 = cb2[1];
        #pragma unroll
        for (int j = 0; j < 16; ++j){
            float h = fmaxf(fmaf(q, cW1[j], cb1[j]), 0.f);
            o0 = fmaf(h, cW2[j*2+0], o0);
            o1 = fmaf(h, cW2[j*2+1], o1);
        }
        float2* o2 = (float2*)out;
        o2[samp] = make_float2(o0, o1);
    }
}

extern "C" void kernel_launch(void* const* d_in, const int* in_sizes, int n_in,
                              void* d_out, int out_size, void* d_ws, size_t ws_size,
                              hipStream_t stream)
{
    const float* text  = (const float*)d_in[0];
    const float* image = (const float*)d_in[1];
    const float* tW1   = (const float*)d_in[2];
    const float* tb1   = (const float*)d_in[3];
    const float* tW2   = (const float*)d_in[4];
    const float* tb2   = (const float*)d_in[5];
    const float* iW1   = (const float*)d_in[6];
    const float* ib1   = (const float*)d_in[7];
    const float* iW2   = (const float*)d_in[8];
    const float* ib2   = (const float*)d_in[9];
    const float* qw    = (const float*)d_in[10];
    const float* cW1   = (const float*)d_in[11];
    const float* cb1   = (const float*)d_in[12];
    const float* cW2   = (const float*)d_in[13];
    const float* cb2   = (const float*)d_in[14];

    float* A = (float*)d_ws;          // 256 floats
    int B = in_sizes[0] / 16;

    qnn_precompute_A<<<1, 256, 0, stream>>>(qw, A);

    int block = 256;
    int grid = (B + block - 1) / block;
    qnn_main<<<grid, block, 0, stream>>>(
        text, image, tW1, tb1, tW2, tb2, iW1, ib1, iW2, ib2,
        A, cW1, cb1, cW2, cb2, (float*)d_out, B);
}

// Round 6
// 236.681 us; speedup vs baseline: 1.3922x; 1.0397x over previous
//
#include <hip/hip_runtime.h>
#include <math.h>

#define NQ 4
#define NL 2

typedef __attribute__((ext_vector_type(8))) short short8v;  // 8 x bf16 (4 VGPRs)
typedef __attribute__((ext_vector_type(4))) float f32x4;

__device__ inline unsigned short f2bf(float x){
    unsigned u = __float_as_uint(x);
    u += 0x7FFFu + ((u >> 16) & 1u);          // RNE
    return (unsigned short)(u >> 16);
}
__device__ inline float bf2f(unsigned short h){
    return __uint_as_float(((unsigned)h) << 16);
}
// staging-path split (strided gather -> small array, static indices)
__device__ inline void split8(const float* x, short8v& hi, short8v& lo){
    #pragma unroll
    for (int e = 0; e < 8; ++e){
        unsigned short h = f2bf(x[e]);
        hi[e] = (short)h;
        lo[e] = (short)f2bf(x[e] - bf2f(h));
    }
}
// hot-path split: two float4 -> hi/lo bf16x8, fully scalar SSA
#define PK(i, val) { unsigned short h_ = f2bf(val); hi[i] = (short)h_; lo[i] = (short)f2bf((val) - bf2f(h_)); }
__device__ inline void pack8(float4 a, float4 b, short8v& hi, short8v& lo){
    PK(0, a.x) PK(1, a.y) PK(2, a.z) PK(3, a.w)
    PK(4, b.x) PK(5, b.y) PK(6, b.z) PK(7, b.w)
}
#undef PK

// ---------------------------------------------------------------------------
// Kernel 1: precompute A = Re(M^dagger D M)  (unchanged, verified)
// ---------------------------------------------------------------------------
__global__ void qnn_precompute_A(const float* __restrict__ qw, float* __restrict__ A)
{
    __shared__ float Mre[16][16];
    __shared__ float Mim[16][16];
    int t = threadIdx.x;
    if (t < 16) {
        int j = t;
        float re[16], im[16];
        for (int b = 0; b < 16; ++b) { re[b] = (b == j) ? 1.f : 0.f; im[b] = 0.f; }
        for (int l = 0; l < NL; ++l) {
            for (int i = 0; i < NQ; ++i) {
                float phi   = qw[(l*NQ + i)*3 + 0];
                float theta = qw[(l*NQ + i)*3 + 1];
                float omega = qw[(l*NQ + i)*3 + 2];
                float ct, st; sincosf(0.5f*theta, &st, &ct);
                float ap = 0.5f*(phi + omega);
                float am = 0.5f*(phi - omega);
                float cap, sap, cam, sam;
                sincosf(ap, &sap, &cap);
                sincosf(am, &sam, &cam);
                float u00r =  cap*ct, u00i = -sap*ct;
                float u01r = -cam*st, u01i = -sam*st;
                float u10r =  cam*st, u10i = -sam*st;
                float u11r =  cap*ct, u11i =  sap*ct;
                int mask = 1 << (3 - i);
                for (int b = 0; b < 16; ++b) {
                    if (b & mask) continue;
                    int b1 = b | mask;
                    float a0r = re[b],  a0i = im[b];
                    float a1r = re[b1], a1i = im[b1];
                    re[b]  = u00r*a0r - u00i*a0i + u01r*a1r - u01i*a1i;
                    im[b]  = u00r*a0i + u00i*a0r + u01r*a1i + u01i*a1r;
                    re[b1] = u10r*a0r - u10i*a0i + u11r*a1r - u11i*a1i;
                    im[b1] = u10r*a0i + u10i*a0r + u11r*a1i + u11i*a1r;
                }
            }
            for (int b = 0; b < 16; ++b) {
                float sgn = 1.f;
                if ((b & 0xC) == 0xC) sgn = -sgn;
                if ((b & 0x6) == 0x6) sgn = -sgn;
                if ((b & 0x3) == 0x3) sgn = -sgn;
                re[b] *= sgn; im[b] *= sgn;
            }
        }
        for (int b = 0; b < 16; ++b) { Mre[j][b] = re[b]; Mim[j][b] = im[b]; }
    }
    __syncthreads();
    {
        int j = t >> 4, k = t & 15;
        float s = 0.f;
        #pragma unroll
        for (int b = 0; b < 16; ++b) {
            float sg = (b & 8) ? -1.f : 1.f;
            s += sg * (Mre[j][b]*Mre[k][b] + Mim[j][b]*Mim[k][b]);
        }
        A[j*16 + k] = s;
    }
}

// ---------------------------------------------------------------------------
// shared helpers
// ---------------------------------------------------------------------------
__device__ inline void po_update(float (&po)[4][4], const f32x4& cc, const float4& w2){
    #pragma unroll
    for (int r = 0; r < 4; ++r){
        float h = fmaxf(cc[r], 0.f);
        po[r][0] = fmaf(h, w2.x, po[r][0]);
        po[r][1] = fmaf(h, w2.y, po[r][1]);
        po[r][2] = fmaf(h, w2.z, po[r][2]);
        po[r][3] = fmaf(h, w2.w, po[r][3]);
    }
}
// bias-at-epilogue variant (keeps bias regs out of the MFMA window)
__device__ inline void po_updateB(float (&po)[4][4], const f32x4& cc, const float4& w2, float bb){
    #pragma unroll
    for (int r = 0; r < 4; ++r){
        float h = fmaxf(cc[r] + bb, 0.f);
        po[r][0] = fmaf(h, w2.x, po[r][0]);
        po[r][1] = fmaf(h, w2.y, po[r][1]);
        po[r][2] = fmaf(h, w2.z, po[r][2]);
        po[r][3] = fmaf(h, w2.w, po[r][3]);
    }
}
__device__ inline void reduce_po(float (&po)[4][4]){
    #pragma unroll
    for (int r = 0; r < 4; ++r)
        #pragma unroll
        for (int o = 0; o < 4; ++o){
            float v = po[r][o];
            v += __shfl_xor(v, 1);
            v += __shfl_xor(v, 2);
            v += __shfl_xor(v, 4);
            v += __shfl_xor(v, 8);
            po[r][o] = v;
        }
}
__device__ inline float4 pick_row(const float (&po)[4][4], int c){
    float4 v;
    if      (c == 0) v = make_float4(po[0][0], po[0][1], po[0][2], po[0][3]);
    else if (c == 1) v = make_float4(po[1][0], po[1][1], po[1][2], po[1][3]);
    else if (c == 2) v = make_float4(po[2][0], po[2][1], po[2][2], po[2][3]);
    else             v = make_float4(po[3][0], po[3][1], po[3][2], po[3][3]);
    return v;
}

#define STEP3(ACC, BH, BL, AH, AL)                                          \
    ACC = __builtin_amdgcn_mfma_f32_16x16x32_bf16(AH, BH, ACC, 0, 0, 0);    \
    ACC = __builtin_amdgcn_mfma_f32_16x16x32_bf16(AH, BL, ACC, 0, 0, 0);    \
    ACC = __builtin_amdgcn_mfma_f32_16x16x32_bf16(AL, BH, ACC, 0, 0, 0);

// ---------------------------------------------------------------------------
// Kernel 2a: feats only (phase-1 of R5). Writes feats[B] float4 to workspace.
// Removing phase-2 (psi/A-matvec/head) from the allocation problem is the
// structural spill fix after R2-R5's incremental containment (157->40MB
// scratch). Bias moved to epilogue so the MFMA window holds only:
// 6 input float4 (24) + Ah/Al (8) + bh/bl (8) + addressing (~10) ~ 50 arch
// regs; accumulators a0..a5 live in the AGPR half.
// ---------------------------------------------------------------------------
__global__ __launch_bounds__(256, 4) void qnn_feats(
    const float* __restrict__ text, const float* __restrict__ image,
    const float* __restrict__ tW1, const float* __restrict__ tb1,
    const float* __restrict__ tW2,
    const float* __restrict__ iW1, const float* __restrict__ ib1,
    const float* __restrict__ iW2,
    float* __restrict__ featsOut, int B)
{
    __shared__ short8v WimgH[4][2][64];   // [nt][ks][lane]  8 KB
    __shared__ short8v WimgL[4][2][64];   //                 8 KB
    __shared__ short8v WtxtH[2][64];      //                 2 KB
    __shared__ short8v WtxtL[2][64];      //                 2 KB

    const int t    = threadIdx.x;
    const int lane = t & 63;
    const int wv   = t >> 6;
    const int g    = lane >> 4;
    const int c    = lane & 15;
    const long long blockBase = (long long)blockIdx.x * 256;

    // ---------- cooperative weight-fragment staging (once per block) --------
    #pragma unroll
    for (int s = t; s < 512; s += 256){
        int nt = s >> 7, ks = (s >> 6) & 1, ln = s & 63;
        int gg = ln >> 4, cc_ = ln & 15;
        float x[8];
        #pragma unroll
        for (int e = 0; e < 8; ++e){
            int k = ks*32 + 8*gg + e;
            x[e] = (k < 48) ? iW1[k*64 + nt*16 + cc_] : 0.f;
        }
        short8v h, l; split8(x, h, l);
        WimgH[nt][ks][ln] = h;
        WimgL[nt][ks][ln] = l;
    }
    if (t < 128){
        int nt = t >> 6, ln = t & 63;
        int gg = ln >> 4, cc_ = ln & 15;
        float x[8];
        #pragma unroll
        for (int e = 0; e < 8; ++e){
            int k = 8*gg + e;
            x[e] = (k < 16) ? tW1[k*32 + nt*16 + cc_] : 0.f;
        }
        short8v h, l; split8(x, h, l);
        WtxtH[nt][ln] = h;
        WtxtL[nt][ln] = l;
    }
    __syncthreads();

    #pragma unroll 1
    for (int ms = 0; ms < 4; ++ms){
        long long m = blockBase + wv*64 + ms*16 + c;
        if (m >= B) m = B - 1;
        const float* irow = image + m*48;
        const float* trow = text  + m*16;

        const float4 z = make_float4(0.f, 0.f, 0.f, 0.f);
        float4 i0a = *(const float4*)(irow + 8*g);
        float4 i0b = *(const float4*)(irow + 8*g + 4);
        float4 i1a = z, i1b = z, t0a = z, t0b = z;
        if (g < 2){
            i1a = *(const float4*)(irow + 32 + 8*g);
            i1b = *(const float4*)(irow + 36 + 8*g);
            t0a = *(const float4*)(trow + 8*g);
            t0b = *(const float4*)(trow + 8*g + 4);
        }

        f32x4 a0 = { 0.f, 0.f, 0.f, 0.f };
        f32x4 a1 = { 0.f, 0.f, 0.f, 0.f };
        f32x4 a2 = { 0.f, 0.f, 0.f, 0.f };
        f32x4 a3 = { 0.f, 0.f, 0.f, 0.f };
        f32x4 a4 = { 0.f, 0.f, 0.f, 0.f };
        f32x4 a5 = { 0.f, 0.f, 0.f, 0.f };

        short8v Ah, Al;

        // ---- phase 1: image k 0..31 ----
        pack8(i0a, i0b, Ah, Al);
        { short8v bh = WimgH[0][0][lane], bl = WimgL[0][0][lane]; STEP3(a0, bh, bl, Ah, Al) }
        { short8v bh = WimgH[1][0][lane], bl = WimgL[1][0][lane]; STEP3(a1, bh, bl, Ah, Al) }
        { short8v bh = WimgH[2][0][lane], bl = WimgL[2][0][lane]; STEP3(a2, bh, bl, Ah, Al) }
        { short8v bh = WimgH[3][0][lane], bl = WimgL[3][0][lane]; STEP3(a3, bh, bl, Ah, Al) }
        __builtin_amdgcn_sched_barrier(0);

        // ---- phase 2: image k 32..47 (zero-padded to 64) ----
        pack8(i1a, i1b, Ah, Al);
        { short8v bh = WimgH[0][1][lane], bl = WimgL[0][1][lane]; STEP3(a0, bh, bl, Ah, Al) }
        { short8v bh = WimgH[1][1][lane], bl = WimgL[1][1][lane]; STEP3(a1, bh, bl, Ah, Al) }
        { short8v bh = WimgH[2][1][lane], bl = WimgL[2][1][lane]; STEP3(a2, bh, bl, Ah, Al) }
        { short8v bh = WimgH[3][1][lane], bl = WimgL[3][1][lane]; STEP3(a3, bh, bl, Ah, Al) }
        __builtin_amdgcn_sched_barrier(0);

        // ---- phase 3: text k 0..15 (zero-padded to 32) ----
        pack8(t0a, t0b, Ah, Al);
        { short8v bh = WtxtH[0][lane], bl = WtxtL[0][lane]; STEP3(a4, bh, bl, Ah, Al) }
        { short8v bh = WtxtH[1][lane], bl = WtxtL[1][lane]; STEP3(a5, bh, bl, Ah, Al) }
        __builtin_amdgcn_sched_barrier(0);

        // ---- epilogue: bias + relu + layer-2, reduce over 16 neuron lanes --
        float po[4][4];
        #pragma unroll
        for (int r = 0; r < 4; ++r)
            #pragma unroll
            for (int o = 0; o < 4; ++o) po[r][o] = 0.f;

        { float4 w2 = *(const float4*)(iW2 + (c)*4);      po_updateB(po, a0, w2, ib1[c]); }
        { float4 w2 = *(const float4*)(iW2 + (16+c)*4);   po_updateB(po, a1, w2, ib1[16+c]); }
        { float4 w2 = *(const float4*)(iW2 + (32+c)*4);   po_updateB(po, a2, w2, ib1[32+c]); }
        { float4 w2 = *(const float4*)(iW2 + (48+c)*4);   po_updateB(po, a3, w2, ib1[48+c]); }
        { float4 w2 = *(const float4*)(tW2 + (c)*4);      po_updateB(po, a4, w2, tb1[c]); }
        { float4 w2 = *(const float4*)(tW2 + (16+c)*4);   po_updateB(po, a5, w2, tb1[16+c]); }

        reduce_po(po);
        if (c < 4){
            long long sIdx = blockBase + wv*64 + ms*16 + 4*g + c;
            if (sIdx < B)
                ((float4*)featsOut)[sIdx] = pick_row(po, c);
        }
        __builtin_amdgcn_sched_barrier(0);
    }
}

// ---------------------------------------------------------------------------
// Kernel 2b: quantum quadratic form + head, 1 thread/sample, lean registers.
// A (16x16) staged into 1 KB LDS; all-lane same-address reads broadcast free.
// ---------------------------------------------------------------------------
__global__ __launch_bounds__(256, 8) void qnn_tail(
    const float* __restrict__ feats,
    const float* __restrict__ tb2, const float* __restrict__ ib2,
    const float* __restrict__ Aq,
    const float* __restrict__ cW1, const float* __restrict__ cb1,
    const float* __restrict__ cW2, const float* __restrict__ cb2,
    float* __restrict__ out, int B)
{
    __shared__ float As[256];
    const int t = threadIdx.x;
    As[t] = Aq[t];
    __syncthreads();

    long long samp = (long long)blockIdx.x * 256 + t;
    if (samp >= B) return;

    float4 f4 = ((const float4*)feats)[samp];
    float acc[4];
    acc[0] = tb2[0] + ib2[0] + f4.x;
    acc[1] = tb2[1] + ib2[1] + f4.y;
    acc[2] = tb2[2] + ib2[2] + f4.z;
    acc[3] = tb2[3] + ib2[3] + f4.w;

    float cth[4], sth[4];
    #pragma unroll
    for (int i = 0; i < 4; ++i){
        float f = acc[i] * 0.25f;
        __sincosf(f, &sth[i], &cth[i]);
    }
    float p01[4] = { cth[0]*cth[1], cth[0]*sth[1], sth[0]*cth[1], sth[0]*sth[1] };
    float p23[4] = { cth[2]*cth[3], cth[2]*sth[3], sth[2]*cth[3], sth[2]*sth[3] };
    float psi[16];
    #pragma unroll
    for (int x = 0; x < 4; ++x)
        #pragma unroll
        for (int y = 0; y < 4; ++y)
            psi[x*4+y] = p01[x] * p23[y];

    float q = 0.f;
    #pragma unroll
    for (int j = 0; j < 16; ++j){
        float row = 0.f;
        #pragma unroll
        for (int k = 0; k < 16; ++k) row = fmaf(As[j*16+k], psi[k], row);
        q = fmaf(psi[j], row, q);
    }

    float o0 = cb2[0], o1 = cb2[1];
    #pragma unroll
    for (int j = 0; j < 16; ++j){
        float h = fmaxf(fmaf(q, cW1[j], cb1[j]), 0.f);
        o0 = fmaf(h, cW2[j*2+0], o0);
        o1 = fmaf(h, cW2[j*2+1], o1);
    }
    float2* o2 = (float2*)out;
    o2[samp] = make_float2(o0, o1);
}

// ---------------------------------------------------------------------------
// Fallback: R5's verified fused kernel (used if workspace too small for feats)
// ---------------------------------------------------------------------------
__global__ __launch_bounds__(256, 4) void qnn_fused(
    const float* __restrict__ text, const float* __restrict__ image,
    const float* __restrict__ tW1, const float* __restrict__ tb1,
    const float* __restrict__ tW2, const float* __restrict__ tb2,
    const float* __restrict__ iW1, const float* __restrict__ ib1,
    const float* __restrict__ iW2, const float* __restrict__ ib2,
    const float* __restrict__ A,
    const float* __restrict__ cW1, const float* __restrict__ cb1,
    const float* __restrict__ cW2, const float* __restrict__ cb2,
    float* __restrict__ out, int B)
{
    __shared__ short8v WimgH[4][2][64];
    __shared__ short8v WimgL[4][2][64];
    __shared__ short8v WtxtH[2][64];
    __shared__ short8v WtxtL[2][64];
    __shared__ float4  feats[256];

    const int t    = threadIdx.x;
    const int lane = t & 63;
    const int wv   = t >> 6;
    const int g    = lane >> 4;
    const int c    = lane & 15;
    const long long blockBase = (long long)blockIdx.x * 256;

    #pragma unroll
    for (int s = t; s < 512; s += 256){
        int nt = s >> 7, ks = (s >> 6) & 1, ln = s & 63;
        int gg = ln >> 4, cc_ = ln & 15;
        float x[8];
        #pragma unroll
        for (int e = 0; e < 8; ++e){
            int k = ks*32 + 8*gg + e;
            x[e] = (k < 48) ? iW1[k*64 + nt*16 + cc_] : 0.f;
        }
        short8v h, l; split8(x, h, l);
        WimgH[nt][ks][ln] = h;
        WimgL[nt][ks][ln] = l;
    }
    if (t < 128){
        int nt = t >> 6, ln = t & 63;
        int gg = ln >> 4, cc_ = ln & 15;
        float x[8];
        #pragma unroll
        for (int e = 0; e < 8; ++e){
            int k = 8*gg + e;
            x[e] = (k < 16) ? tW1[k*32 + nt*16 + cc_] : 0.f;
        }
        short8v h, l; split8(x, h, l);
        WtxtH[nt][ln] = h;
        WtxtL[nt][ln] = l;
    }
    __syncthreads();

    const float bI0 = ib1[c],      bI1 = ib1[16 + c];
    const float bI2 = ib1[32 + c], bI3 = ib1[48 + c];
    const float bT0 = tb1[c],      bT1 = tb1[16 + c];

    #pragma unroll 1
    for (int ms = 0; ms < 4; ++ms){
        long long m = blockBase + wv*64 + ms*16 + c;
        if (m >= B) m = B - 1;
        const float* irow = image + m*48;
        const float* trow = text  + m*16;

        const float4 z = make_float4(0.f, 0.f, 0.f, 0.f);
        float4 i0a = *(const float4*)(irow + 8*g);
        float4 i0b = *(const float4*)(irow + 8*g + 4);
        float4 i1a = z, i1b = z, t0a = z, t0b = z;
        if (g < 2){
            i1a = *(const float4*)(irow + 32 + 8*g);
            i1b = *(const float4*)(irow + 36 + 8*g);
            t0a = *(const float4*)(trow + 8*g);
            t0b = *(const float4*)(trow + 8*g + 4);
        }

        f32x4 a0 = { bI0, bI0, bI0, bI0 };
        f32x4 a1 = { bI1, bI1, bI1, bI1 };
        f32x4 a2 = { bI2, bI2, bI2, bI2 };
        f32x4 a3 = { bI3, bI3, bI3, bI3 };
        f32x4 a4 = { bT0, bT0, bT0, bT0 };
        f32x4 a5 = { bT1, bT1, bT1, bT1 };

        short8v Ah, Al;

        pack8(i0a, i0b, Ah, Al);
        { short8v bh = WimgH[0][0][lane], bl = WimgL[0][0][lane]; STEP3(a0, bh, bl, Ah, Al) }
        { short8v bh = WimgH[1][0][lane], bl = WimgL[1][0][lane]; STEP3(a1, bh, bl, Ah, Al) }
        { short8v bh = WimgH[2][0][lane], bl = WimgL[2][0][lane]; STEP3(a2, bh, bl, Ah, Al) }
        { short8v bh = WimgH[3][0][lane], bl = WimgL[3][0][lane]; STEP3(a3, bh, bl, Ah, Al) }
        __builtin_amdgcn_sched_barrier(0);

        pack8(i1a, i1b, Ah, Al);
        { short8v bh = WimgH[0][1][lane], bl = WimgL[0][1][lane]; STEP3(a0, bh, bl, Ah, Al) }
        { short8v bh = WimgH[1][1][lane], bl = WimgL[1][1][lane]; STEP3(a1, bh, bl, Ah, Al) }
        { short8v bh = WimgH[2][1][lane], bl = WimgL[2][1][lane]; STEP3(a2, bh, bl, Ah, Al) }
        { short8v bh = WimgH[3][1][lane], bl = WimgL[3][1][lane]; STEP3(a3, bh, bl, Ah, Al) }
        __builtin_amdgcn_sched_barrier(0);

        pack8(t0a, t0b, Ah, Al);
        { short8v bh = WtxtH[0][lane], bl = WtxtL[0][lane]; STEP3(a4, bh, bl, Ah, Al) }
        { short8v bh = WtxtH[1][lane], bl = WtxtL[1][lane]; STEP3(a5, bh, bl, Ah, Al) }
        __builtin_amdgcn_sched_barrier(0);

        float po[4][4];
        #pragma unroll
        for (int r = 0; r < 4; ++r)
            #pragma unroll
            for (int o = 0; o < 4; ++o) po[r][o] = 0.f;

        { float4 w2 = *(const float4*)(iW2 + (c)*4);      po_update(po, a0, w2); }
        { float4 w2 = *(const float4*)(iW2 + (16+c)*4);   po_update(po, a1, w2); }
        { float4 w2 = *(const float4*)(iW2 + (32+c)*4);   po_update(po, a2, w2); }
        { float4 w2 = *(const float4*)(iW2 + (48+c)*4);   po_update(po, a3, w2); }
        { float4 w2 = *(const float4*)(tW2 + (c)*4);      po_update(po, a4, w2); }
        { float4 w2 = *(const float4*)(tW2 + (16+c)*4);   po_update(po, a5, w2); }

        reduce_po(po);
        if (c < 4)
            feats[wv*64 + ms*16 + 4*g + c] = pick_row(po, c);
        __builtin_amdgcn_sched_barrier(0);
    }

    __syncthreads();

    long long samp = blockBase + t;
    if (samp < B){
        float4 f4 = feats[t];
        float acc[4];
        acc[0] = tb2[0] + ib2[0] + f4.x;
        acc[1] = tb2[1] + ib2[1] + f4.y;
        acc[2] = tb2[2] + ib2[2] + f4.z;
        acc[3] = tb2[3] + ib2[3] + f4.w;

        float cth[4], sth[4];
        #pragma unroll
        for (int i = 0; i < 4; ++i){
            float f = acc[i] * 0.25f;
            __sincosf(f, &sth[i], &cth[i]);
        }
        float p01[4] = { cth[0]*cth[1], cth[0]*sth[1], sth[0]*cth[1], sth[0]*sth[1] };
        float p23[4] = { cth[2]*cth[3], cth[2]*sth[3], sth[2]*cth[3], sth[2]*sth[3] };
        float psi[16];
        #pragma unroll
        for (int x = 0; x < 4; ++x)
            #pragma unroll
            for (int y = 0; y < 4; ++y)
                psi[x*4+y] = p01[x] * p23[y];

        float q = 0.f;
        #pragma unroll
        for (int j = 0; j < 16; ++j){
            float row = 0.f;
            #pragma unroll
            for (int k = 0; k < 16; ++k) row = fmaf(A[j*16+k], psi[k], row);
            q = fmaf(psi[j], row, q);
        }

        float o0 = cb2[0], o1 = cb2[1];
        #pragma unroll
        for (int j = 0; j < 16; ++j){
            float h = fmaxf(fmaf(q, cW1[j], cb1[j]), 0.f);
            o0 = fmaf(h, cW2[j*2+0], o0);
            o1 = fmaf(h, cW2[j*2+1], o1);
        }
        float2* o2 = (float2*)out;
        o2[samp] = make_float2(o0, o1);
    }
}

extern "C" void kernel_launch(void* const* d_in, const int* in_sizes, int n_in,
                              void* d_out, int out_size, void* d_ws, size_t ws_size,
                              hipStream_t stream)
{
    const float* text  = (const float*)d_in[0];
    const float* image = (const float*)d_in[1];
    const float* tW1   = (const float*)d_in[2];
    const float* tb1   = (const float*)d_in[3];
    const float* tW2   = (const float*)d_in[4];
    const float* tb2   = (const float*)d_in[5];
    const float* iW1   = (const float*)d_in[6];
    const float* ib1   = (const float*)d_in[7];
    const float* iW2   = (const float*)d_in[8];
    const float* ib2   = (const float*)d_in[9];
    const float* qw    = (const float*)d_in[10];
    const float* cW1   = (const float*)d_in[11];
    const float* cb1   = (const float*)d_in[12];
    const float* cW2   = (const float*)d_in[13];
    const float* cb2   = (const float*)d_in[14];

    float* A = (float*)d_ws;          // 256 floats
    int B = in_sizes[0] / 16;

    qnn_precompute_A<<<1, 256, 0, stream>>>(qw, A);

    int block = 256;
    int grid = (B + block - 1) / block;
    size_t need = 1024 + (size_t)B * 16;   // A (1 KB) + feats (B x float4)

    if (ws_size >= need){
        float* featsWs = (float*)((char*)d_ws + 1024);
        qnn_feats<<<grid, block, 0, stream>>>(
            text, image, tW1, tb1, tW2, iW1, ib1, iW2, featsWs, B);
        qnn_tail<<<grid, block, 0, stream>>>(
            featsWs, tb2, ib2, A, cW1, cb1, cW2, cb2, (float*)d_out, B);
    } else {
        qnn_fused<<<grid, block, 0, stream>>>(
            text, image, tW1, tb1, tW2, tb2, iW1, ib1, iW2, ib2,
            A, cW1, cb1, cW2, cb2, (float*)d_out, B);
    }
}

// Round 7
// 229.392 us; speedup vs baseline: 1.4365x; 1.0318x over previous
//
#include <hip/hip_runtime.h>
#include <math.h>

#define NQ 4
#define NL 2

typedef __attribute__((ext_vector_type(8))) short short8v;  // 8 x bf16 (4 VGPRs)
typedef __attribute__((ext_vector_type(4))) float f32x4;

__device__ inline unsigned short f2bf(float x){
    unsigned u = __float_as_uint(x);
    u += 0x7FFFu + ((u >> 16) & 1u);          // RNE
    return (unsigned short)(u >> 16);
}
__device__ inline float bf2f(unsigned short h){
    return __uint_as_float(((unsigned)h) << 16);
}
// staging-path split (strided gather -> small array, static indices)
__device__ inline void split8(const float* x, short8v& hi, short8v& lo){
    #pragma unroll
    for (int e = 0; e < 8; ++e){
        unsigned short h = f2bf(x[e]);
        hi[e] = (short)h;
        lo[e] = (short)f2bf(x[e] - bf2f(h));
    }
}
// hot-path split: two float4 -> hi/lo bf16x8, fully scalar SSA
#define PK(i, val) { unsigned short h_ = f2bf(val); hi[i] = (short)h_; lo[i] = (short)f2bf((val) - bf2f(h_)); }
__device__ inline void pack8(float4 a, float4 b, short8v& hi, short8v& lo){
    PK(0, a.x) PK(1, a.y) PK(2, a.z) PK(3, a.w)
    PK(4, b.x) PK(5, b.y) PK(6, b.z) PK(7, b.w)
}
#undef PK

// ---------------------------------------------------------------------------
// Kernel 1: precompute A = Re(M^dagger D M)  (unchanged, verified)
// ---------------------------------------------------------------------------
__global__ void qnn_precompute_A(const float* __restrict__ qw, float* __restrict__ A)
{
    __shared__ float Mre[16][16];
    __shared__ float Mim[16][16];
    int t = threadIdx.x;
    if (t < 16) {
        int j = t;
        float re[16], im[16];
        for (int b = 0; b < 16; ++b) { re[b] = (b == j) ? 1.f : 0.f; im[b] = 0.f; }
        for (int l = 0; l < NL; ++l) {
            for (int i = 0; i < NQ; ++i) {
                float phi   = qw[(l*NQ + i)*3 + 0];
                float theta = qw[(l*NQ + i)*3 + 1];
                float omega = qw[(l*NQ + i)*3 + 2];
                float ct, st; sincosf(0.5f*theta, &st, &ct);
                float ap = 0.5f*(phi + omega);
                float am = 0.5f*(phi - omega);
                float cap, sap, cam, sam;
                sincosf(ap, &sap, &cap);
                sincosf(am, &sam, &cam);
                float u00r =  cap*ct, u00i = -sap*ct;
                float u01r = -cam*st, u01i = -sam*st;
                float u10r =  cam*st, u10i = -sam*st;
                float u11r =  cap*ct, u11i =  sap*ct;
                int mask = 1 << (3 - i);
                for (int b = 0; b < 16; ++b) {
                    if (b & mask) continue;
                    int b1 = b | mask;
                    float a0r = re[b],  a0i = im[b];
                    float a1r = re[b1], a1i = im[b1];
                    re[b]  = u00r*a0r - u00i*a0i + u01r*a1r - u01i*a1i;
                    im[b]  = u00r*a0i + u00i*a0r + u01r*a1i + u01i*a1r;
                    re[b1] = u10r*a0r - u10i*a0i + u11r*a1r - u11i*a1i;
                    im[b1] = u10r*a0i + u10i*a0r + u11r*a1i + u11i*a1r;
                }
            }
            for (int b = 0; b < 16; ++b) {
                float sgn = 1.f;
                if ((b & 0xC) == 0xC) sgn = -sgn;
                if ((b & 0x6) == 0x6) sgn = -sgn;
                if ((b & 0x3) == 0x3) sgn = -sgn;
                re[b] *= sgn; im[b] *= sgn;
            }
        }
        for (int b = 0; b < 16; ++b) { Mre[j][b] = re[b]; Mim[j][b] = im[b]; }
    }
    __syncthreads();
    {
        int j = t >> 4, k = t & 15;
        float s = 0.f;
        #pragma unroll
        for (int b = 0; b < 16; ++b) {
            float sg = (b & 8) ? -1.f : 1.f;
            s += sg * (Mre[j][b]*Mre[k][b] + Mim[j][b]*Mim[k][b]);
        }
        A[j*16 + k] = s;
    }
}

// ---------------------------------------------------------------------------
// shared helpers
// ---------------------------------------------------------------------------
__device__ inline void po_update(float (&po)[4][4], const f32x4& cc, const float4& w2){
    #pragma unroll
    for (int r = 0; r < 4; ++r){
        float h = fmaxf(cc[r], 0.f);
        po[r][0] = fmaf(h, w2.x, po[r][0]);
        po[r][1] = fmaf(h, w2.y, po[r][1]);
        po[r][2] = fmaf(h, w2.z, po[r][2]);
        po[r][3] = fmaf(h, w2.w, po[r][3]);
    }
}
// bias-at-epilogue variant (keeps bias regs out of the MFMA window)
__device__ inline void po_updateB(float (&po)[4][4], const f32x4& cc, const float4& w2, float bb){
    #pragma unroll
    for (int r = 0; r < 4; ++r){
        float h = fmaxf(cc[r] + bb, 0.f);
        po[r][0] = fmaf(h, w2.x, po[r][0]);
        po[r][1] = fmaf(h, w2.y, po[r][1]);
        po[r][2] = fmaf(h, w2.z, po[r][2]);
        po[r][3] = fmaf(h, w2.w, po[r][3]);
    }
}
__device__ inline void reduce_po(float (&po)[4][4]){
    #pragma unroll
    for (int r = 0; r < 4; ++r)
        #pragma unroll
        for (int o = 0; o < 4; ++o){
            float v = po[r][o];
            v += __shfl_xor(v, 1);
            v += __shfl_xor(v, 2);
            v += __shfl_xor(v, 4);
            v += __shfl_xor(v, 8);
            po[r][o] = v;
        }
}
__device__ inline float4 pick_row(const float (&po)[4][4], int c){
    float4 v;
    if      (c == 0) v = make_float4(po[0][0], po[0][1], po[0][2], po[0][3]);
    else if (c == 1) v = make_float4(po[1][0], po[1][1], po[1][2], po[1][3]);
    else if (c == 2) v = make_float4(po[2][0], po[2][1], po[2][2], po[2][3]);
    else             v = make_float4(po[3][0], po[3][1], po[3][2], po[3][3]);
    return v;
}

#define STEP3(ACC, BH, BL, AH, AL)                                          \
    ACC = __builtin_amdgcn_mfma_f32_16x16x32_bf16(AH, BH, ACC, 0, 0, 0);    \
    ACC = __builtin_amdgcn_mfma_f32_16x16x32_bf16(AH, BL, ACC, 0, 0, 0);    \
    ACC = __builtin_amdgcn_mfma_f32_16x16x32_bf16(AL, BH, ACC, 0, 0, 0);

// ---------------------------------------------------------------------------
// Kernel 2a: feats only, SOFTWARE-PIPELINED (T14 issue-early).
// R6 diagnosis: 72us with VALUBusy 29% / MfmaUtil 8.6% -- each M-tile's 6
// global float4 loads were issued immediately before pack8 consumed them,
// exposing ~500cy of load latency 4x per wave with only 3 waves/SIMD of
// cover. This version prefetches tile ms+1's inputs (named regs n0..n5, no
// runtime-indexed arrays) at the TOP of iteration ms so they fly under the
// current tile's pack8 + 30 MFMAs + epilogue (~1500cy).
// __launch_bounds__(256,3): measured occupancy was already 3 waves/SIMD at
// (256,4), so this costs nothing and gives the allocator ~40 more unified
// regs to hold the prefetch buffers + kill the residual ~2-3 reg spill
// (WRITE_SIZE 18.4MB vs 8.4MB real -> target 8.6MB).
// ---------------------------------------------------------------------------
__global__ __launch_bounds__(256, 3) void qnn_feats(
    const float* __restrict__ text, const float* __restrict__ image,
    const float* __restrict__ tW1, const float* __restrict__ tb1,
    const float* __restrict__ tW2,
    const float* __restrict__ iW1, const float* __restrict__ ib1,
    const float* __restrict__ iW2,
    float* __restrict__ featsOut, int B)
{
    __shared__ short8v WimgH[4][2][64];   // [nt][ks][lane]  8 KB
    __shared__ short8v WimgL[4][2][64];   //                 8 KB
    __shared__ short8v WtxtH[2][64];      //                 2 KB
    __shared__ short8v WtxtL[2][64];      //                 2 KB

    const int t    = threadIdx.x;
    const int lane = t & 63;
    const int wv   = t >> 6;
    const int g    = lane >> 4;
    const int c    = lane & 15;
    const long long blockBase = (long long)blockIdx.x * 256;
    const long long base = blockBase + wv*64 + c;

    // ---------- cooperative weight-fragment staging (once per block) --------
    #pragma unroll
    for (int s = t; s < 512; s += 256){
        int nt = s >> 7, ks = (s >> 6) & 1, ln = s & 63;
        int gg = ln >> 4, cc_ = ln & 15;
        float x[8];
        #pragma unroll
        for (int e = 0; e < 8; ++e){
            int k = ks*32 + 8*gg + e;
            x[e] = (k < 48) ? iW1[k*64 + nt*16 + cc_] : 0.f;
        }
        short8v h, l; split8(x, h, l);
        WimgH[nt][ks][ln] = h;
        WimgL[nt][ks][ln] = l;
    }
    if (t < 128){
        int nt = t >> 6, ln = t & 63;
        int gg = ln >> 4, cc_ = ln & 15;
        float x[8];
        #pragma unroll
        for (int e = 0; e < 8; ++e){
            int k = 8*gg + e;
            x[e] = (k < 16) ? tW1[k*32 + nt*16 + cc_] : 0.f;
        }
        short8v h, l; split8(x, h, l);
        WtxtH[nt][ln] = h;
        WtxtL[nt][ln] = l;
    }
    __syncthreads();

    const float4 z = make_float4(0.f, 0.f, 0.f, 0.f);

    // ---------------- prologue: load tile 0 into cur ------------------------
    float4 c0, c1, c2, c3, c4, c5;
    {
        long long m = base; if (m >= B) m = B - 1;
        const float* irow = image + m*48;
        const float* trow = text  + m*16;
        c0 = *(const float4*)(irow + 8*g);
        c1 = *(const float4*)(irow + 8*g + 4);
        c2 = z; c3 = z; c4 = z; c5 = z;
        if (g < 2){
            c2 = *(const float4*)(irow + 32 + 8*g);
            c3 = *(const float4*)(irow + 36 + 8*g);
            c4 = *(const float4*)(trow + 8*g);
            c5 = *(const float4*)(trow + 8*g + 4);
        }
    }

    float4 n0 = z, n1 = z, n2 = z, n3 = z, n4 = z, n5 = z;

    // ---------------- main loop: 4 M-tiles, prefetch depth 1 ----------------
    #pragma unroll 1
    for (int ms = 0; ms < 4; ++ms){
        // prefetch next tile's inputs FIRST (in flight under pack8+MFMA+epi)
        if (ms < 3){
            long long m = base + (ms + 1)*16; if (m >= B) m = B - 1;
            const float* irow = image + m*48;
            const float* trow = text  + m*16;
            n0 = *(const float4*)(irow + 8*g);
            n1 = *(const float4*)(irow + 8*g + 4);
            if (g < 2){
                n2 = *(const float4*)(irow + 32 + 8*g);
                n3 = *(const float4*)(irow + 36 + 8*g);
                n4 = *(const float4*)(trow + 8*g);
                n5 = *(const float4*)(trow + 8*g + 4);
            }
        }

        // pack current tile (consumes c0..c5)
        short8v A0h, A0l, A1h, A1l, ATh, ATl;
        pack8(c0, c1, A0h, A0l);
        pack8(c2, c3, A1h, A1l);
        pack8(c4, c5, ATh, ATl);

        f32x4 a0 = { 0.f, 0.f, 0.f, 0.f };
        f32x4 a1 = { 0.f, 0.f, 0.f, 0.f };
        f32x4 a2 = { 0.f, 0.f, 0.f, 0.f };
        f32x4 a3 = { 0.f, 0.f, 0.f, 0.f };
        f32x4 a4 = { 0.f, 0.f, 0.f, 0.f };
        f32x4 a5 = { 0.f, 0.f, 0.f, 0.f };

        // ---- phase 1: image k 0..31 ----
        { short8v bh = WimgH[0][0][lane], bl = WimgL[0][0][lane]; STEP3(a0, bh, bl, A0h, A0l) }
        { short8v bh = WimgH[1][0][lane], bl = WimgL[1][0][lane]; STEP3(a1, bh, bl, A0h, A0l) }
        { short8v bh = WimgH[2][0][lane], bl = WimgL[2][0][lane]; STEP3(a2, bh, bl, A0h, A0l) }
        { short8v bh = WimgH[3][0][lane], bl = WimgL[3][0][lane]; STEP3(a3, bh, bl, A0h, A0l) }
        __builtin_amdgcn_sched_barrier(0);

        // ---- phase 2: image k 32..47 (zero-padded to 64) ----
        { short8v bh = WimgH[0][1][lane], bl = WimgL[0][1][lane]; STEP3(a0, bh, bl, A1h, A1l) }
        { short8v bh = WimgH[1][1][lane], bl = WimgL[1][1][lane]; STEP3(a1, bh, bl, A1h, A1l) }
        { short8v bh = WimgH[2][1][lane], bl = WimgL[2][1][lane]; STEP3(a2, bh, bl, A1h, A1l) }
        { short8v bh = WimgH[3][1][lane], bl = WimgL[3][1][lane]; STEP3(a3, bh, bl, A1h, A1l) }
        __builtin_amdgcn_sched_barrier(0);

        // ---- phase 3: text k 0..15 (zero-padded to 32) ----
        { short8v bh = WtxtH[0][lane], bl = WtxtL[0][lane]; STEP3(a4, bh, bl, ATh, ATl) }
        { short8v bh = WtxtH[1][lane], bl = WtxtL[1][lane]; STEP3(a5, bh, bl, ATh, ATl) }
        __builtin_amdgcn_sched_barrier(0);

        // ---- epilogue: bias + relu + layer-2, reduce over 16 neuron lanes --
        float po[4][4];
        #pragma unroll
        for (int r = 0; r < 4; ++r)
            #pragma unroll
            for (int o = 0; o < 4; ++o) po[r][o] = 0.f;

        { float4 w2 = *(const float4*)(iW2 + (c)*4);      po_updateB(po, a0, w2, ib1[c]); }
        { float4 w2 = *(const float4*)(iW2 + (16+c)*4);   po_updateB(po, a1, w2, ib1[16+c]); }
        { float4 w2 = *(const float4*)(iW2 + (32+c)*4);   po_updateB(po, a2, w2, ib1[32+c]); }
        { float4 w2 = *(const float4*)(iW2 + (48+c)*4);   po_updateB(po, a3, w2, ib1[48+c]); }
        { float4 w2 = *(const float4*)(tW2 + (c)*4);      po_updateB(po, a4, w2, tb1[c]); }
        { float4 w2 = *(const float4*)(tW2 + (16+c)*4);   po_updateB(po, a5, w2, tb1[16+c]); }

        reduce_po(po);
        if (c < 4){
            long long sIdx = blockBase + wv*64 + ms*16 + 4*g + c;
            if (sIdx < B)
                ((float4*)featsOut)[sIdx] = pick_row(po, c);
        }
        __builtin_amdgcn_sched_barrier(0);

        // rotate prefetch buffers into current
        c0 = n0; c1 = n1; c2 = n2; c3 = n3; c4 = n4; c5 = n5;
    }
}

// ---------------------------------------------------------------------------
// Kernel 2b: quantum quadratic form + head, 1 thread/sample, lean registers.
// ---------------------------------------------------------------------------
__global__ __launch_bounds__(256, 8) void qnn_tail(
    const float* __restrict__ feats,
    const float* __restrict__ tb2, const float* __restrict__ ib2,
    const float* __restrict__ Aq,
    const float* __restrict__ cW1, const float* __restrict__ cb1,
    const float* __restrict__ cW2, const float* __restrict__ cb2,
    float* __restrict__ out, int B)
{
    __shared__ float As[256];
    const int t = threadIdx.x;
    As[t] = Aq[t];
    __syncthreads();

    long long samp = (long long)blockIdx.x * 256 + t;
    if (samp >= B) return;

    float4 f4 = ((const float4*)feats)[samp];
    float acc[4];
    acc[0] = tb2[0] + ib2[0] + f4.x;
    acc[1] = tb2[1] + ib2[1] + f4.y;
    acc[2] = tb2[2] + ib2[2] + f4.z;
    acc[3] = tb2[3] + ib2[3] + f4.w;

    float cth[4], sth[4];
    #pragma unroll
    for (int i = 0; i < 4; ++i){
        float f = acc[i] * 0.25f;
        __sincosf(f, &sth[i], &cth[i]);
    }
    float p01[4] = { cth[0]*cth[1], cth[0]*sth[1], sth[0]*cth[1], sth[0]*sth[1] };
    float p23[4] = { cth[2]*cth[3], cth[2]*sth[3], sth[2]*cth[3], sth[2]*sth[3] };
    float psi[16];
    #pragma unroll
    for (int x = 0; x < 4; ++x)
        #pragma unroll
        for (int y = 0; y < 4; ++y)
            psi[x*4+y] = p01[x] * p23[y];

    float q = 0.f;
    #pragma unroll
    for (int j = 0; j < 16; ++j){
        float row = 0.f;
        #pragma unroll
        for (int k = 0; k < 16; ++k) row = fmaf(As[j*16+k], psi[k], row);
        q = fmaf(psi[j], row, q);
    }

    float o0 = cb2[0], o1 = cb2[1];
    #pragma unroll
    for (int j = 0; j < 16; ++j){
        float h = fmaxf(fmaf(q, cW1[j], cb1[j]), 0.f);
        o0 = fmaf(h, cW2[j*2+0], o0);
        o1 = fmaf(h, cW2[j*2+1], o1);
    }
    float2* o2 = (float2*)out;
    o2[samp] = make_float2(o0, o1);
}

// ---------------------------------------------------------------------------
// Fallback: R5's verified fused kernel (used if workspace too small)
// ---------------------------------------------------------------------------
__global__ __launch_bounds__(256, 4) void qnn_fused(
    const float* __restrict__ text, const float* __restrict__ image,
    const float* __restrict__ tW1, const float* __restrict__ tb1,
    const float* __restrict__ tW2, const float* __restrict__ tb2,
    const float* __restrict__ iW1, const float* __restrict__ ib1,
    const float* __restrict__ iW2, const float* __restrict__ ib2,
    const float* __restrict__ A,
    const float* __restrict__ cW1, const float* __restrict__ cb1,
    const float* __restrict__ cW2, const float* __restrict__ cb2,
    float* __restrict__ out, int B)
{
    __shared__ short8v WimgH[4][2][64];
    __shared__ short8v WimgL[4][2][64];
    __shared__ short8v WtxtH[2][64];
    __shared__ short8v WtxtL[2][64];
    __shared__ float4  feats[256];

    const int t    = threadIdx.x;
    const int lane = t & 63;
    const int wv   = t >> 6;
    const int g    = lane >> 4;
    const int c    = lane & 15;
    const long long blockBase = (long long)blockIdx.x * 256;

    #pragma unroll
    for (int s = t; s < 512; s += 256){
        int nt = s >> 7, ks = (s >> 6) & 1, ln = s & 63;
        int gg = ln >> 4, cc_ = ln & 15;
        float x[8];
        #pragma unroll
        for (int e = 0; e < 8; ++e){
            int k = ks*32 + 8*gg + e;
            x[e] = (k < 48) ? iW1[k*64 + nt*16 + cc_] : 0.f;
        }
        short8v h, l; split8(x, h, l);
        WimgH[nt][ks][ln] = h;
        WimgL[nt][ks][ln] = l;
    }
    if (t < 128){
        int nt = t >> 6, ln = t & 63;
        int gg = ln >> 4, cc_ = ln & 15;
        float x[8];
        #pragma unroll
        for (int e = 0; e < 8; ++e){
            int k = 8*gg + e;
            x[e] = (k < 16) ? tW1[k*32 + nt*16 + cc_] : 0.f;
        }
        short8v h, l; split8(x, h, l);
        WtxtH[nt][ln] = h;
        WtxtL[nt][ln] = l;
    }
    __syncthreads();

    const float bI0 = ib1[c],      bI1 = ib1[16 + c];
    const float bI2 = ib1[32 + c], bI3 = ib1[48 + c];
    const float bT0 = tb1[c],      bT1 = tb1[16 + c];

    #pragma unroll 1
    for (int ms = 0; ms < 4; ++ms){
        long long m = blockBase + wv*64 + ms*16 + c;
        if (m >= B) m = B - 1;
        const float* irow = image + m*48;
        const float* trow = text  + m*16;

        const float4 z = make_float4(0.f, 0.f, 0.f, 0.f);
        float4 i0a = *(const float4*)(irow + 8*g);
        float4 i0b = *(const float4*)(irow + 8*g + 4);
        float4 i1a = z, i1b = z, t0a = z, t0b = z;
        if (g < 2){
            i1a = *(const float4*)(irow + 32 + 8*g);
            i1b = *(const float4*)(irow + 36 + 8*g);
            t0a = *(const float4*)(trow + 8*g);
            t0b = *(const float4*)(trow + 8*g + 4);
        }

        f32x4 a0 = { bI0, bI0, bI0, bI0 };
        f32x4 a1 = { bI1, bI1, bI1, bI1 };
        f32x4 a2 = { bI2, bI2, bI2, bI2 };
        f32x4 a3 = { bI3, bI3, bI3, bI3 };
        f32x4 a4 = { bT0, bT0, bT0, bT0 };
        f32x4 a5 = { bT1, bT1, bT1, bT1 };

        short8v Ah, Al;

        pack8(i0a, i0b, Ah, Al);
        { short8v bh = WimgH[0][0][lane], bl = WimgL[0][0][lane]; STEP3(a0, bh, bl, Ah, Al) }
        { short8v bh = WimgH[1][0][lane], bl = WimgL[1][0][lane]; STEP3(a1, bh, bl, Ah, Al) }
        { short8v bh = WimgH[2][0][lane], bl = WimgL[2][0][lane]; STEP3(a2, bh, bl, Ah, Al) }
        { short8v bh = WimgH[3][0][lane], bl = WimgL[3][0][lane]; STEP3(a3, bh, bl, Ah, Al) }
        __builtin_amdgcn_sched_barrier(0);

        pack8(i1a, i1b, Ah, Al);
        { short8v bh = WimgH[0][1][lane], bl = WimgL[0][1][lane]; STEP3(a0, bh, bl, Ah, Al) }
        { short8v bh = WimgH[1][1][lane], bl = WimgL[1][1][lane]; STEP3(a1, bh, bl, Ah, Al) }
        { short8v bh = WimgH[2][1][lane], bl = WimgL[2][1][lane]; STEP3(a2, bh, bl, Ah, Al) }
        { short8v bh = WimgH[3][1][lane], bl = WimgL[3][1][lane]; STEP3(a3, bh, bl, Ah, Al) }
        __builtin_amdgcn_sched_barrier(0);

        pack8(t0a, t0b, Ah, Al);
        { short8v bh = WtxtH[0][lane], bl = WtxtL[0][lane]; STEP3(a4, bh, bl, Ah, Al) }
        { short8v bh = WtxtH[1][lane], bl = WtxtL[1][lane]; STEP3(a5, bh, bl, Ah, Al) }
        __builtin_amdgcn_sched_barrier(0);

        float po[4][4];
        #pragma unroll
        for (int r = 0; r < 4; ++r)
            #pragma unroll
            for (int o = 0; o < 4; ++o) po[r][o] = 0.f;

        { float4 w2 = *(const float4*)(iW2 + (c)*4);      po_update(po, a0, w2); }
        { float4 w2 = *(const float4*)(iW2 + (16+c)*4);   po_update(po, a1, w2); }
        { float4 w2 = *(const float4*)(iW2 + (32+c)*4);   po_update(po, a2, w2); }
        { float4 w2 = *(const float4*)(iW2 + (48+c)*4);   po_update(po, a3, w2); }
        { float4 w2 = *(const float4*)(tW2 + (c)*4);      po_update(po, a4, w2); }
        { float4 w2 = *(const float4*)(tW2 + (16+c)*4);   po_update(po, a5, w2); }

        reduce_po(po);
        if (c < 4)
            feats[wv*64 + ms*16 + 4*g + c] = pick_row(po, c);
        __builtin_amdgcn_sched_barrier(0);
    }

    __syncthreads();

    long long samp = blockBase + t;
    if (samp < B){
        float4 f4 = feats[t];
        float acc[4];
        acc[0] = tb2[0] + ib2[0] + f4.x;
        acc[1] = tb2[1] + ib2[1] + f4.y;
        acc[2] = tb2[2] + ib2[2] + f4.z;
        acc[3] = tb2[3] + ib2[3] + f4.w;

        float cth[4], sth[4];
        #pragma unroll
        for (int i = 0; i < 4; ++i){
            float f = acc[i] * 0.25f;
            __sincosf(f, &sth[i], &cth[i]);
        }
        float p01[4] = { cth[0]*cth[1], cth[0]*sth[1], sth[0]*cth[1], sth[0]*sth[1] };
        float p23[4] = { cth[2]*cth[3], cth[2]*sth[3], sth[2]*cth[3], sth[2]*sth[3] };
        float psi[16];
        #pragma unroll
        for (int x = 0; x < 4; ++x)
            #pragma unroll
            for (int y = 0; y < 4; ++y)
                psi[x*4+y] = p01[x] * p23[y];

        float q = 0.f;
        #pragma unroll
        for (int j = 0; j < 16; ++j){
            float row = 0.f;
            #pragma unroll
            for (int k = 0; k < 16; ++k) row = fmaf(A[j*16+k], psi[k], row);
            q = fmaf(psi[j], row, q);
        }

        float o0 = cb2[0], o1 = cb2[1];
        #pragma unroll
        for (int j = 0; j < 16; ++j){
            float h = fmaxf(fmaf(q, cW1[j], cb1[j]), 0.f);
            o0 = fmaf(h, cW2[j*2+0], o0);
            o1 = fmaf(h, cW2[j*2+1], o1);
        }
        float2* o2 = (float2*)out;
        o2[samp] = make_float2(o0, o1);
    }
}

extern "C" void kernel_launch(void* const* d_in, const int* in_sizes, int n_in,
                              void* d_out, int out_size, void* d_ws, size_t ws_size,
                              hipStream_t stream)
{
    const float* text  = (const float*)d_in[0];
    const float* image = (const float*)d_in[1];
    const float* tW1   = (const float*)d_in[2];
    const float* tb1   = (const float*)d_in[3];
    const float* tW2   = (const float*)d_in[4];
    const float* tb2   = (const float*)d_in[5];
    const float* iW1   = (const float*)d_in[6];
    const float* ib1   = (const float*)d_in[7];
    const float* iW2   = (const float*)d_in[8];
    const float* ib2   = (const float*)d_in[9];
    const float* qw    = (const float*)d_in[10];
    const float* cW1   = (const float*)d_in[11];
    const float* cb1   = (const float*)d_in[12];
    const float* cW2   = (const float*)d_in[13];
    const float* cb2   = (const float*)d_in[14];

    float* A = (float*)d_ws;          // 256 floats
    int B = in_sizes[0] / 16;

    qnn_precompute_A<<<1, 256, 0, stream>>>(qw, A);

    int block = 256;
    int grid = (B + block - 1) / block;
    size_t need = 1024 + (size_t)B * 16;   // A (1 KB) + feats (B x float4)

    if (ws_size >= need){
        float* featsWs = (float*)((char*)d_ws + 1024);
        qnn_feats<<<grid, block, 0, stream>>>(
            text, image, tW1, tb1, tW2, iW1, ib1, iW2, featsWs, B);
        qnn_tail<<<grid, block, 0, stream>>>(
            featsWs, tb2, ib2, A, cW1, cb1, cW2, cb2, (float*)d_out, B);
    } else {
        qnn_fused<<<grid, block, 0, stream>>>(
            text, image, tW1, tb1, tW2, tb2, iW1, ib1, iW2, ib2,
            A, cW1, cb1, cW2, cb2, (float*)d_out, B);
    }
}